// Round 3
// baseline (509.192 us; speedup 1.0000x reference)
//
#include <hip/hip_runtime.h>
#include <cstdint>
#include <cstddef>

#define Bb 128
#define Tt 2048
#define Dd 512
#define Hh 512
#define Mtot (Bb*Tt)

typedef __attribute__((ext_vector_type(8))) _Float16 h8;
typedef __attribute__((ext_vector_type(4))) _Float16 h4v;
typedef __attribute__((ext_vector_type(4))) float f4;

// ---------------- kernel 1: W -> fp16 ----------------
__global__ void w16_kernel(const float* __restrict__ W, _Float16* __restrict__ W16) {
    int i = blockIdx.x * 256 + threadIdx.x;
    W16[i] = (_Float16)W[i];
}

// ---------------- kernel 1b: mask compaction (deterministic prefix-sum) ------
__global__ void compact_kernel(const int* __restrict__ mask, int* __restrict__ cidx,
                               int* __restrict__ cnt) {
    __shared__ int wsum[4];
    int b = blockIdx.x, tid = threadIdx.x;  // 256 threads
    const int* mrow = mask + (size_t)b * Tt;
    int mv[8], c = 0;
#pragma unroll
    for (int i = 0; i < 8; i++) { mv[i] = mrow[tid * 8 + i]; c += mv[i]; }
    int lane = tid & 63, wv = tid >> 6;
    int inc = c;
#pragma unroll
    for (int off = 1; off < 64; off <<= 1) {
        int n = __shfl_up(inc, off);
        if (lane >= off) inc += n;
    }
    if (lane == 63) wsum[wv] = inc;
    __syncthreads();
    int wbase = 0;
    for (int w = 0; w < wv; w++) wbase += wsum[w];
    int pos = wbase + inc - c;  // exclusive prefix
    int* crow = cidx + (size_t)b * Tt;
#pragma unroll
    for (int i = 0; i < 8; i++)
        if (mv[i]) crow[pos++] = tid * 8 + i;
    if (tid == 255) cnt[b] = wbase + inc;
}

// ---------------- kernel 2: col_t = relu(col @ W^T), fp32 exact ----------------
__global__ void col_proj_kernel(const float* __restrict__ col, const float* __restrict__ W,
                                float* __restrict__ colt) {
    __shared__ float c[Dd];
    int b = blockIdx.x;
    int tid = threadIdx.x;  // 128 threads
    for (int i = tid; i < Dd; i += 128) c[i] = col[b * Dd + i];
    __syncthreads();
    int h = blockIdx.y * 128 + tid;
    const f4* w4 = (const f4*)(W + (size_t)h * Dd);
    float acc = 0.f;
#pragma unroll 8
    for (int k = 0; k < Dd / 4; k++) {
        f4 w = w4[k];
        acc += w.x * c[4 * k] + w.y * c[4 * k + 1] + w.z * c[4 * k + 2] + w.w * c[4 * k + 3];
    }
    colt[b * Hh + h] = fmaxf(acc, 0.f);
}

// ---------------- kernel 3: fused scores GEMM over COMPACTED rows ----------------
__global__ __launch_bounds__(512) void scores_kernel(
    const float* __restrict__ X,        // [B*T][512]
    const _Float16* __restrict__ W16,   // [512][512]
    const float* __restrict__ colt,     // [128][512]
    const int* __restrict__ cidx,       // [B][T] compacted t-indices
    const int* __restrict__ cnt,        // [B]
    float* __restrict__ scores)         // [B*T], pre-zeroed
{
    const int tid = threadIdx.x;
    const int b = blockIdx.x >> 5;      // 32 tiles per b
    const int tile = blockIdx.x & 31;
    const int count = cnt[b];
    const int r0 = tile * 64;
    if (r0 >= count) return;            // uniform early-exit (before any barrier)

    __shared__ _Float16 sW[512 * 32];    // 32KB, swizzled [row][kchunk^((row>>1)&3)]
    __shared__ _Float16 sXhi[64 * 32];   // 4KB
    __shared__ _Float16 sXlo[64 * 32];   // 4KB
    __shared__ float scolt[Hh];          // 2KB
    __shared__ float sred[4][64];        // 1KB

    scolt[tid] = colt[b * Hh + tid];

    const int wave = tid >> 6;
    const int lane = tid & 63;
    const int wm = wave >> 2;   // 0..1
    const int wn = wave & 3;    // 0..3
    const int l16 = lane & 15;
    const int khi = lane >> 4;  // 0..3

    f4 acc[2][8];
#pragma unroll
    for (int i = 0; i < 2; i++)
#pragma unroll
        for (int j = 0; j < 8; j++) {
            f4 z = {0.f, 0.f, 0.f, 0.f};
            acc[i][j] = z;
        }

    const int xrow = tid >> 3;  // 0..63 (local compacted row this thread stages)
    const int xf4  = tid & 7;   // float4 index within 32-float row slice
    const int rl = r0 + xrow;
    const int t_idx = (rl < count) ? cidx[(size_t)b * Tt + rl] : cidx[(size_t)b * Tt];
    const float* xbase = X + ((size_t)b * Tt + t_idx) * Dd;

    for (int ks = 0; ks < 16; ks++) {
        const int k0 = ks * 32;
        __syncthreads();  // protect LDS from previous iteration's readers
        // ---- stage W: thread tid stages row `tid`, 64B = 4 x 16B chunks ----
        {
            const uint4* s4 = (const uint4*)(W16 + (size_t)tid * Dd + k0);
#pragma unroll
            for (int cc = 0; cc < 4; cc++) {
                uint4 v = s4[cc];
                int cs = cc ^ ((tid >> 1) & 3);
                *(uint4*)((char*)sW + tid * 64 + cs * 16) = v;
            }
        }
        // ---- stage X (gathered row): float4 -> fp16 hi/lo split ----
        {
            const float4 xv = *(const float4*)(xbase + k0 + xf4 * 4);
            float xs[4] = {xv.x, xv.y, xv.z, xv.w};
            _Float16 hi[4], lo[4];
#pragma unroll
            for (int j = 0; j < 4; j++) {
                hi[j] = (_Float16)xs[j];
                lo[j] = (_Float16)(xs[j] - (float)hi[j]);
            }
            int kc = xf4 >> 1;
            int kcs = kc ^ ((xrow >> 1) & 3);
            int byteoff = xrow * 64 + kcs * 16 + (xf4 & 1) * 8;
            *(h4v*)((char*)sXhi + byteoff) = *(h4v*)hi;
            *(h4v*)((char*)sXlo + byteoff) = *(h4v*)lo;
        }
        __syncthreads();

        // ---- fragment loads + MFMA ----
        h8 ahi[2], alo[2];
#pragma unroll
        for (int mr = 0; mr < 2; mr++) {
            int row = wm * 32 + mr * 16 + l16;
            int kb = (khi ^ ((row >> 1) & 3)) * 16;
            ahi[mr] = *(const h8*)((const char*)sXhi + row * 64 + kb);
            alo[mr] = *(const h8*)((const char*)sXlo + row * 64 + kb);
        }
#pragma unroll
        for (int nr = 0; nr < 8; nr++) {
            int row = wn * 128 + nr * 16 + l16;
            int kb = (khi ^ ((row >> 1) & 3)) * 16;
            h8 bf = *(const h8*)((const char*)sW + row * 64 + kb);
            acc[0][nr] = __builtin_amdgcn_mfma_f32_16x16x32_f16(ahi[0], bf, acc[0][nr], 0, 0, 0);
            acc[1][nr] = __builtin_amdgcn_mfma_f32_16x16x32_f16(ahi[1], bf, acc[1][nr], 0, 0, 0);
            acc[0][nr] = __builtin_amdgcn_mfma_f32_16x16x32_f16(alo[0], bf, acc[0][nr], 0, 0, 0);
            acc[1][nr] = __builtin_amdgcn_mfma_f32_16x16x32_f16(alo[1], bf, acc[1][nr], 0, 0, 0);
        }
    }

    // ---- epilogue: relu * colt, reduce over N ----
    float rs[2][4];
#pragma unroll
    for (int mr = 0; mr < 2; mr++)
#pragma unroll
        for (int r = 0; r < 4; r++) rs[mr][r] = 0.f;

#pragma unroll
    for (int nr = 0; nr < 8; nr++) {
        float cv = scolt[wn * 128 + nr * 16 + l16];
#pragma unroll
        for (int mr = 0; mr < 2; mr++)
#pragma unroll
            for (int r = 0; r < 4; r++)
                rs[mr][r] += fmaxf(acc[mr][nr][r], 0.f) * cv;
    }
#pragma unroll
    for (int mr = 0; mr < 2; mr++)
#pragma unroll
        for (int r = 0; r < 4; r++) {
            float v = rs[mr][r];
            v += __shfl_xor(v, 1);
            v += __shfl_xor(v, 2);
            v += __shfl_xor(v, 4);
            v += __shfl_xor(v, 8);
            rs[mr][r] = v;
        }
    if (l16 == 0) {
#pragma unroll
        for (int mr = 0; mr < 2; mr++)
#pragma unroll
            for (int r = 0; r < 4; r++) {
                int row = wm * 32 + mr * 16 + (lane >> 4) * 4 + r;
                sred[wn][row] = rs[mr][r];   // unique writer per (wn,row): deterministic
            }
    }
    __syncthreads();
    if (tid < 64) {
        int r = r0 + tid;
        if (r < count) {
            float s = sred[0][tid] + sred[1][tid] + sred[2][tid] + sred[3][tid];
            scores[(size_t)b * Tt + cidx[(size_t)b * Tt + r]] = s;  // mask==1 here
        }
    }
}

// ---------------- kernel 4: softmax per b (IN-PLACE) + copy col into cat ------
// attn may alias scores: every thread's reads of srow complete before the
// barrier-separated reduction; writes to arow happen only after it.
__global__ void softmax_kernel(const float* __restrict__ scores, const float* __restrict__ col,
                               float* __restrict__ attn, float* __restrict__ out) {
    __shared__ float sm[256];
    int b = blockIdx.x, tid = threadIdx.x;
    const float* srow = scores + (size_t)b * Tt;
    float v[8];
#pragma unroll
    for (int i = 0; i < 8; i++) v[i] = srow[tid + i * 256];
    float mx = -1e30f;
#pragma unroll
    for (int i = 0; i < 8; i++) mx = fmaxf(mx, v[i]);
    sm[tid] = mx;
    __syncthreads();
    for (int s = 128; s > 0; s >>= 1) {
        if (tid < s) sm[tid] = fmaxf(sm[tid], sm[tid + s]);
        __syncthreads();
    }
    float M = sm[0];
    __syncthreads();
    float e[8];
    float sum = 0.f;
#pragma unroll
    for (int i = 0; i < 8; i++) {
        e[i] = __expf(v[i] - M);
        sum += e[i];
    }
    sm[tid] = sum;
    __syncthreads();
    for (int s = 128; s > 0; s >>= 1) {
        if (tid < s) sm[tid] += sm[tid + s];
        __syncthreads();
    }
    float inv = 1.f / sm[0];
    float* arow = attn + (size_t)b * Tt;
#pragma unroll
    for (int i = 0; i < 8; i++) arow[tid + i * 256] = e[i] * inv;
    for (int d = tid; d < Dd; d += 256) out[(size_t)b * 1024 + d] = col[(size_t)b * Dd + d];
}

// ---------------- kernel 5: partial weighted sums over t (4 chunks of 512) ----
__global__ void wsum_kernel(const float* __restrict__ attn, const float* __restrict__ X,
                            float* __restrict__ part) {
    int dh = blockIdx.x;   // 0..1
    int tc = blockIdx.y;   // 0..3
    int b  = blockIdx.z;   // 0..127
    int tid = threadIdx.x; // 256
    int d = dh * 256 + tid;
    __shared__ float sa[512];
    int t0 = tc * 512;
    sa[tid] = attn[(size_t)b * Tt + t0 + tid];
    sa[tid + 256] = attn[(size_t)b * Tt + t0 + 256 + tid];
    __syncthreads();
    float acc = 0.f;
    const float* xp = X + ((size_t)b * Tt + t0) * Dd + d;
#pragma unroll 4
    for (int j = 0; j < 512; j++) acc += sa[j] * xp[(size_t)j * Dd];
    part[((size_t)b * 4 + tc) * Dd + d] = acc;
}

// ---------------- kernel 6: combine partials, write both outputs ----------------
__global__ void combine_kernel(const float* __restrict__ part, float* __restrict__ out) {
    int i = blockIdx.x * 256 + threadIdx.x;  // < 65536
    int b = i >> 9, d = i & 511;
    float s = 0.f;
#pragma unroll
    for (int tc = 0; tc < 4; tc++) s += part[((size_t)b * 4 + tc) * Dd + d];
    out[(size_t)b * 1024 + 512 + d] = s;                 // cat section, second half
    out[(size_t)Bb * 1024 + (size_t)b * 512 + d] = s;    // attention_output section
}

extern "C" void kernel_launch(void* const* d_in, const int* in_sizes, int n_in,
                              void* d_out, int out_size, void* d_ws, size_t ws_size,
                              hipStream_t stream) {
    const float* col  = (const float*)d_in[0];   // [128,512]
    const float* X    = (const float*)d_in[1];   // [128,2048,512]
    const int*   mask = (const int*)d_in[2];     // [128,2048]
    const float* W    = (const float*)d_in[3];   // [512,512]
    float* out = (float*)d_out;

    // Total ws usage: 3841 KB (stay well under the 4.75MB envelope proven in R1).
    char* ws = (char*)d_ws;
    _Float16* W16   = (_Float16*)ws;                     // 0    .. 512K
    float*    colt  = (float*)(ws + (512 << 10));        // 512K .. 768K
    float*    scores= (float*)(ws + (768 << 10));        // 768K .. 1792K
    float*    attn  = scores;                            // softmax in-place
    float*    part  = (float*)(ws + (1792 << 10));       // 1792K.. 2816K
    int*      cidx  = (int*)(ws + (2816 << 10));         // 2816K.. 3840K
    int*      cnt   = (int*)(ws + (3840 << 10));         // 3840K.. +512B

    hipMemsetAsync(scores, 0, Mtot * sizeof(float), stream);  // masked rows stay 0
    hipLaunchKernelGGL(w16_kernel, dim3(Hh * Dd / 256), dim3(256), 0, stream, W, W16);
    hipLaunchKernelGGL(compact_kernel, dim3(Bb), dim3(256), 0, stream, mask, cidx, cnt);
    hipLaunchKernelGGL(col_proj_kernel, dim3(Bb, Hh / 128), dim3(128), 0, stream, col, W, colt);
    hipLaunchKernelGGL(scores_kernel, dim3(Bb * 32), dim3(512), 0, stream,
                       X, W16, colt, cidx, cnt, scores);
    hipLaunchKernelGGL(softmax_kernel, dim3(Bb), dim3(256), 0, stream, scores, col, attn, out);
    hipLaunchKernelGGL(wsum_kernel, dim3(2, 4, Bb), dim3(256), 0, stream, attn, X, part);
    hipLaunchKernelGGL(combine_kernel, dim3(65536 / 256), dim3(256), 0, stream, part, out);
}